// Round 12
// baseline (159.694 us; speedup 1.0000x reference)
//
#include <hip/hip_runtime.h>

#define DIM 256  // 2^8 amplitudes

typedef _Float16 f16x8 __attribute__((ext_vector_type(8)));
typedef _Float16 f16x4 __attribute__((ext_vector_type(4)));
typedef float f32x4 __attribute__((ext_vector_type(4)));

// 5 layer matrices, 4x4 complex each, row-major M[r*4+c]
__device__ float2 g_M[5 * 16];
// B = U^T (fp16 hi/lo split), packed in MFMA-fragment order:
// tile t = col-tile (0..31), s = k-step (0..7): element (lane, h):
// lane = oct*16+c16 holds col c16, k = s*32 + oct*8 + h. 1 KB per tile-step.
__device__ __align__(16) _Float16 g_Bph[32 * 8 * 64 * 8];
__device__ __align__(16) _Float16 g_Bpl[32 * 8 * 64 * 8];

__device__ inline float2 cmulc(float2 a, float2 b) {
    return make_float2(a.x * b.x - a.y * b.y, a.x * b.y + a.y * b.x);
}
__device__ inline float2 caddc(float2 a, float2 b) {
    return make_float2(a.x + b.x, a.y + b.y);
}

// ---------------- setup: build the 5 SU(4) gate matrices ----------------

__device__ void mat_u3(float t, float p, float l, float2* U) {
    float s, c;
    sincosf(0.5f * t, &s, &c);
    float sp, cp, sl, cl, spl, cpl;
    sincosf(p, &sp, &cp);
    sincosf(l, &sl, &cl);
    sincosf(p + l, &spl, &cpl);
    U[0] = make_float2(c, 0.f);
    U[1] = make_float2(-cl * s, -sl * s);
    U[2] = make_float2(cp * s, sp * s);
    U[3] = make_float2(cpl * c, spl * c);
}
__device__ void mat_ry(float t, float2* U) {
    float s, c;
    sincosf(0.5f * t, &s, &c);
    U[0] = make_float2(c, 0.f); U[1] = make_float2(-s, 0.f);
    U[2] = make_float2(s, 0.f); U[3] = make_float2(c, 0.f);
}
__device__ void mat_rz(float t, float2* U) {
    float s, c;
    sincosf(0.5f * t, &s, &c);
    U[0] = make_float2(c, -s); U[1] = make_float2(0.f, 0.f);
    U[2] = make_float2(0.f, 0.f); U[3] = make_float2(c, s);
}
__device__ void mat_I2(float2* U) {
    U[0] = make_float2(1.f, 0.f); U[1] = make_float2(0.f, 0.f);
    U[2] = make_float2(0.f, 0.f); U[3] = make_float2(1.f, 0.f);
}
__device__ void kron4(const float2* A, const float2* B, float2* K) {
    for (int i0 = 0; i0 < 2; ++i0)
        for (int i1 = 0; i1 < 2; ++i1)
            for (int j0 = 0; j0 < 2; ++j0)
                for (int j1 = 0; j1 < 2; ++j1)
                    K[(2 * i0 + i1) * 4 + (2 * j0 + j1)] = cmulc(A[i0 * 2 + j0], B[i1 * 2 + j1]);
}
__device__ void mm4(const float2* A, const float2* B, float2* C) {
    for (int r = 0; r < 4; ++r)
        for (int c = 0; c < 4; ++c) {
            float2 acc = make_float2(0.f, 0.f);
            for (int k = 0; k < 4; ++k) acc = caddc(acc, cmulc(A[r * 4 + k], B[k * 4 + c]));
            C[r * 4 + c] = acc;
        }
}
__device__ void swap_rows(float2* M, int r1, int r2) {
    for (int c = 0; c < 4; ++c) {
        float2 t = M[r1 * 4 + c]; M[r1 * 4 + c] = M[r2 * 4 + c]; M[r2 * 4 + c] = t;
    }
}

__global__ void qsvdd_setup(const float* __restrict__ w) {
    int l = threadIdx.x;
    if (l >= 5) return;
    const float* p = w + l * 15;
    float2 A[4], Bm[4], K[16], M[16], T[16];
    mat_u3(p[0], p[1], p[2], A);
    mat_u3(p[3], p[4], p[5], Bm);
    kron4(A, Bm, M);
    swap_rows(M, 2, 3);                       // CNOT01 @ M
    mat_ry(p[6], A); mat_rz(p[7], Bm);
    kron4(A, Bm, K); mm4(K, M, T);
    swap_rows(T, 1, 3);                       // CNOT10 @ M
    mat_ry(p[8], A); mat_I2(Bm);
    kron4(A, Bm, K); mm4(K, T, M);
    swap_rows(M, 2, 3);                       // CNOT01 @ M
    mat_u3(p[9], p[10], p[11], A);
    mat_u3(p[12], p[13], p[14], Bm);
    kron4(A, Bm, K); mm4(K, M, T);
    for (int i = 0; i < 16; ++i) g_M[l * 16 + i] = T[i];
}

// ---------------- circuit machinery (R8-validated, named registers) ----------------

__device__ __forceinline__ void cmadf(float2& a, float mx, float my, float2 v) {
    a.x = fmaf(mx, v.x, a.x);
    a.x = fmaf(-my, v.y, a.x);
    a.y = fmaf(mx, v.y, a.y);
    a.y = fmaf(my, v.x, a.y);
}
__device__ __forceinline__ float2 cmulf(float mx, float my, float2 v) {
    float2 r;
    r.x = mx * v.x; r.x = fmaf(-my, v.y, r.x);
    r.y = mx * v.y; r.y = fmaf(my, v.x, r.y);
    return r;
}
__device__ __forceinline__ float bperm(int ba, float s) {
    return __int_as_float(__builtin_amdgcn_ds_bpermute(ba, __float_as_int(s)));
}

#define GQ(A0, A1, A2, A3)                                                        \
    {                                                                             \
        float2 t0 = cmulf(m0.x, m0.y, A0);                                        \
        cmadf(t0, m1.x, m1.y, A1); cmadf(t0, m2.x, m2.y, A2); cmadf(t0, m3.x, m3.y, A3);   \
        float2 t1 = cmulf(m4.x, m4.y, A0);                                        \
        cmadf(t1, m5.x, m5.y, A1); cmadf(t1, m6.x, m6.y, A2); cmadf(t1, m7.x, m7.y, A3);   \
        float2 t2 = cmulf(m8.x, m8.y, A0);                                        \
        cmadf(t2, m9.x, m9.y, A1); cmadf(t2, m10.x, m10.y, A2); cmadf(t2, m11.x, m11.y, A3); \
        float2 t3 = cmulf(m12.x, m12.y, A0);                                      \
        cmadf(t3, m13.x, m13.y, A1); cmadf(t3, m14.x, m14.y, A2); cmadf(t3, m15.x, m15.y, A3); \
        A0 = t0; A1 = t1; A2 = t2; A3 = t3;                                       \
    }

#define G_32 { GQ(v0,v4,v8,v12)  GQ(v1,v5,v9,v13)  GQ(v2,v6,v10,v14) GQ(v3,v7,v11,v15) }
#define G_10 { GQ(v0,v1,v2,v3)   GQ(v4,v5,v6,v7)   GQ(v8,v9,v10,v11) GQ(v12,v13,v14,v15) }
#define G_21 { GQ(v0,v2,v4,v6)   GQ(v1,v3,v5,v7)   GQ(v8,v10,v12,v14) GQ(v9,v11,v13,v15) }
#define G_03 { GQ(v0,v8,v1,v9)   GQ(v2,v10,v3,v11) GQ(v4,v12,v5,v13) GQ(v6,v14,v7,v15) }
#define G_20 { GQ(v0,v1,v4,v5)   GQ(v2,v3,v6,v7)   GQ(v8,v9,v12,v13) GQ(v10,v11,v14,v15) }
#define G_13 { GQ(v0,v8,v2,v10)  GQ(v1,v9,v3,v11)  GQ(v4,v12,v6,v14) GQ(v5,v13,v7,v15) }
#define G_02 { GQ(v0,v4,v1,v5)   GQ(v2,v6,v3,v7)   GQ(v8,v12,v9,v13) GQ(v10,v14,v11,v15) }
#define G_30 { GQ(v0,v1,v8,v9)   GQ(v2,v3,v10,v11) GQ(v4,v5,v12,v13) GQ(v6,v7,v14,v15) }
#define G_23 { GQ(v0,v8,v4,v12)  GQ(v1,v9,v5,v13)  GQ(v2,v10,v6,v14) GQ(v3,v11,v7,v15) }
#define G_31 { GQ(v0,v2,v8,v10)  GQ(v1,v3,v9,v11)  GQ(v4,v6,v12,v14) GQ(v5,v7,v13,v15) }
#define G_12 { GQ(v0,v4,v2,v6)   GQ(v1,v5,v3,v7)   GQ(v8,v12,v10,v14) GQ(v9,v13,v11,v15) }

#define BSW(VA, VB, PB, BA)                                                       \
    {                                                                             \
        float sx = (PB) ? VA.x : VB.x, sy = (PB) ? VA.y : VB.y;                   \
        float rx = bperm(BA, sx), ry = bperm(BA, sy);                             \
        VA.x = (PB) ? rx : VA.x; VA.y = (PB) ? ry : VA.y;                         \
        VB.x = (PB) ? VB.x : rx; VB.y = (PB) ? VB.y : ry;                         \
    }

#define SW0(PB, BA) { BSW(v0,v1,PB,BA) BSW(v2,v3,PB,BA) BSW(v4,v5,PB,BA) BSW(v6,v7,PB,BA) \
                      BSW(v8,v9,PB,BA) BSW(v10,v11,PB,BA) BSW(v12,v13,PB,BA) BSW(v14,v15,PB,BA) }
#define SW1(PB, BA) { BSW(v0,v2,PB,BA) BSW(v1,v3,PB,BA) BSW(v4,v6,PB,BA) BSW(v5,v7,PB,BA) \
                      BSW(v8,v10,PB,BA) BSW(v9,v11,PB,BA) BSW(v12,v14,PB,BA) BSW(v13,v15,PB,BA) }
#define SW2(PB, BA) { BSW(v0,v4,PB,BA) BSW(v1,v5,PB,BA) BSW(v2,v6,PB,BA) BSW(v3,v7,PB,BA) \
                      BSW(v8,v12,PB,BA) BSW(v9,v13,PB,BA) BSW(v10,v14,PB,BA) BSW(v11,v15,PB,BA) }
#define SW3(PB, BA) { BSW(v0,v8,PB,BA) BSW(v1,v9,PB,BA) BSW(v2,v10,PB,BA) BSW(v3,v11,PB,BA) \
                      BSW(v4,v12,PB,BA) BSW(v5,v13,PB,BA) BSW(v6,v14,PB,BA) BSW(v7,v15,PB,BA) }

#define LOADM(L)                                                                  \
    {                                                                             \
        m0  = g_M[(L)*16+0];  m1  = g_M[(L)*16+1];  m2  = g_M[(L)*16+2];  m3  = g_M[(L)*16+3];  \
        m4  = g_M[(L)*16+4];  m5  = g_M[(L)*16+5];  m6  = g_M[(L)*16+6];  m7  = g_M[(L)*16+7];  \
        m8  = g_M[(L)*16+8];  m9  = g_M[(L)*16+9];  m10 = g_M[(L)*16+10]; m11 = g_M[(L)*16+11]; \
        m12 = g_M[(L)*16+12]; m13 = g_M[(L)*16+13]; m14 = g_M[(L)*16+14]; m15 = g_M[(L)*16+15]; \
    }

#define RUN_CIRCUIT                                                               \
    LOADM(0);                                                                     \
    G_32; G_10;                                                                   \
    SW3(p3, ba3); SW2(p2, ba2); SW1(p1, ba1); SW0(p0, ba0);                       \
    G_32; G_10;                                                                   \
    G_21;                                                                         \
    SW3(p3, ba3);                                                                 \
    G_03;                                                                         \
    SW1(p3, ba3); SW2(p0, ba0);                                                   \
    G_21;                                                                         \
    SW0(p2, ba2); SW3(p1, ba1);                                                   \
    G_03;                                                                         \
    LOADM(1);                                                                     \
    G_32;                                                                         \
    SW2(p1, ba1);                                                                 \
    G_20;                                                                         \
    SW3(p0, ba0);                                                                 \
    G_13;                                                                         \
    SW0(p3, ba3); SW2(p2, ba2);                                                   \
    G_02;                                                                         \
    G_30;                                                                         \
    SW3(p2, ba2);                                                                 \
    G_23;                                                                         \
    SW2(p1, ba1);                                                                 \
    G_21;                                                                         \
    SW0(p3, ba3); SW3(p0, ba0);                                                   \
    G_03;                                                                         \
    LOADM(2);                                                                     \
    G_31;                                                                         \
    SW2(p3, ba3); SW0(p0, ba0);                                                   \
    G_20;                                                                         \
    G_03; G_12;                                                                   \
    LOADM(3);                                                                     \
    G_31; G_20;                                                                   \
    G_03; G_12;                                                                   \
    LOADM(4);                                                                     \
    G_32;
// final layout: reg-index bits r0..r3 <-> amp bits {7,3,1,5};
// lane bits q0..q3 <-> amp bits {6,0,2,4}   (validated by R6/R8 passes)

// ---------------- build_u: U columns -> packed MFMA-fragment B ----------------

__device__ __forceinline__ int pidx(int n, int c) {
    // n = permuted col (0..511), c = k (0..255) -> packed fragment index
    const int t = n >> 4, c16 = n & 15;
    const int s = c >> 5, oct = (c >> 3) & 3, h = c & 7;
    return (((t * 8 + s) * 64) + oct * 16 + c16) * 8 + h;
}

__device__ __forceinline__ void wru(float2 vv, int rb, int qb, int c) {
    const int a = ((rb & 1) << 7) | (((rb >> 1) & 1) << 3) | (((rb >> 2) & 1) << 1) |
                  (((rb >> 3) & 1) << 5) | qb;
    const int b7 = (a >> 7) & 1, b6 = (a >> 6) & 1, b5 = (a >> 5) & 1, b4 = (a >> 4) & 1;
    const int b3 = (a >> 3) & 1, b2 = (a >> 2) & 1, b1 = (a >> 1) & 1, b0 = a & 1;
    const int g = (b7 << 5) | (b6 << 4) | (b4 << 3) | (b3 << 2) | (b2 << 1) | b0;
    const int n = g * 8 + (((b5 << 1) | b1) << 1);
    const int i0 = pidx(n, c), i1 = pidx(n + 1, c);
    const _Float16 hr = (_Float16)vv.x, hi = (_Float16)vv.y;
    g_Bph[i0] = hr;
    g_Bph[i1] = hi;
    g_Bpl[i0] = (_Float16)((vv.x - (float)hr) * 2048.f);
    g_Bpl[i1] = (_Float16)((vv.y - (float)hi) * 2048.f);
}

__global__ __launch_bounds__(256) void build_u() {
    const int lane = threadIdx.x & 63;
    const int q = lane & 15;
    const int c = ((int)blockIdx.x * 4 + (threadIdx.x >> 6)) * 4 + (lane >> 4);

    const int ba0 = (lane ^ 1) << 2, ba1 = (lane ^ 2) << 2;
    const int ba2 = (lane ^ 4) << 2, ba3 = (lane ^ 8) << 2;
    const bool p0 = lane & 1, p1 = lane & 2, p2 = lane & 4, p3 = lane & 8;

    // basis state e_c  (amp index = r*16 + q)
    float2 v0, v1, v2, v3, v4, v5, v6, v7, v8, v9, v10, v11, v12, v13, v14, v15;
    v0  = make_float2((0*16+q)  == c ? 1.f : 0.f, 0.f);
    v1  = make_float2((1*16+q)  == c ? 1.f : 0.f, 0.f);
    v2  = make_float2((2*16+q)  == c ? 1.f : 0.f, 0.f);
    v3  = make_float2((3*16+q)  == c ? 1.f : 0.f, 0.f);
    v4  = make_float2((4*16+q)  == c ? 1.f : 0.f, 0.f);
    v5  = make_float2((5*16+q)  == c ? 1.f : 0.f, 0.f);
    v6  = make_float2((6*16+q)  == c ? 1.f : 0.f, 0.f);
    v7  = make_float2((7*16+q)  == c ? 1.f : 0.f, 0.f);
    v8  = make_float2((8*16+q)  == c ? 1.f : 0.f, 0.f);
    v9  = make_float2((9*16+q)  == c ? 1.f : 0.f, 0.f);
    v10 = make_float2((10*16+q) == c ? 1.f : 0.f, 0.f);
    v11 = make_float2((11*16+q) == c ? 1.f : 0.f, 0.f);
    v12 = make_float2((12*16+q) == c ? 1.f : 0.f, 0.f);
    v13 = make_float2((13*16+q) == c ? 1.f : 0.f, 0.f);
    v14 = make_float2((14*16+q) == c ? 1.f : 0.f, 0.f);
    v15 = make_float2((15*16+q) == c ? 1.f : 0.f, 0.f);

    float2 m0, m1, m2, m3, m4, m5, m6, m7, m8, m9, m10, m11, m12, m13, m14, m15;
    RUN_CIRCUIT;

    const int qb = ((q & 1) << 6) | (((q >> 1) & 1) << 0) | (((q >> 2) & 1) << 2) |
                   (((q >> 3) & 1) << 4);
    wru(v0, 0, qb, c);   wru(v1, 1, qb, c);   wru(v2, 2, qb, c);   wru(v3, 3, qb, c);
    wru(v4, 4, qb, c);   wru(v5, 5, qb, c);   wru(v6, 6, qb, c);   wru(v7, 7, qb, c);
    wru(v8, 8, qb, c);   wru(v9, 9, qb, c);   wru(v10, 10, qb, c); wru(v11, 11, qb, c);
    wru(v12, 12, qb, c); wru(v13, 13, qb, c); wru(v14, 14, qb, c); wru(v15, 15, qb, c);
}

// ---------------- main: LDS-free MFMA GEMM (A in registers) + fused expvals ----------------
//
// A is loaded DIRECTLY in MFMA fragment order (lane l: row l&15, k-window
// oct*8 — 16 rows x 128 B contiguous segments, fully coalesced), normalized
// in-register (ssq + shfl_xor(16,32) across the 4 lanes sharing a row), and
// fp16 hi/lo split in registers. Zero LDS, zero barriers -> occupancy is
// VGPR-bound. Col-chunk = 64 (4 tiles) keeps acc at 32 VGPRs; 8 chunks.
// 3-term MFMA + expval epilogue identical to R9/R11 (validated).

__device__ __forceinline__ float xorf(float v, unsigned m) {
    return __int_as_float(__float_as_int(v) ^ (int)m);
}

__global__ __launch_bounds__(256, 3) void qsvdd_main(const float* __restrict__ x,
                                                     float* __restrict__ out) {
    const int lane = threadIdx.x & 63;
    const int w = threadIdx.x >> 6;
    const int c16 = lane & 15;
    const int oct = lane >> 4;
    const size_t rowblk = (size_t)blockIdx.x * 4 + w;  // 16-row group, one per wave

    // ---- load A fragments (fp32), in-register norm, fp16 hi/lo split ----
    const float* ax = x + rowblk * 16 * 256 + (size_t)c16 * 256 + oct * 8;
    f32x4 av[16];
#pragma unroll
    for (int s = 0; s < 8; ++s) {
        av[2 * s]     = __builtin_nontemporal_load(reinterpret_cast<const f32x4*>(ax + s * 32));
        av[2 * s + 1] = __builtin_nontemporal_load(reinterpret_cast<const f32x4*>(ax + s * 32 + 4));
    }
    float ssq = 0.f;
#pragma unroll
    for (int i = 0; i < 16; ++i) {
        ssq = fmaf(av[i].x, av[i].x, ssq);
        ssq = fmaf(av[i].y, av[i].y, ssq);
        ssq = fmaf(av[i].z, av[i].z, ssq);
        ssq = fmaf(av[i].w, av[i].w, ssq);
    }
    ssq += __shfl_xor(ssq, 16, 64);
    ssq += __shfl_xor(ssq, 32, 64);
    const float inv = rsqrtf(ssq);

    f16x8 ah[8], al[8];
#pragma unroll
    for (int s = 0; s < 8; ++s) {
        const f32x4 lo = av[2 * s] * inv;
        const f32x4 hi = av[2 * s + 1] * inv;
        f16x8 h, l;
        h[0] = (_Float16)lo.x; h[1] = (_Float16)lo.y; h[2] = (_Float16)lo.z; h[3] = (_Float16)lo.w;
        h[4] = (_Float16)hi.x; h[5] = (_Float16)hi.y; h[6] = (_Float16)hi.z; h[7] = (_Float16)hi.w;
        l[0] = (_Float16)((lo.x - (float)h[0]) * 2048.f);
        l[1] = (_Float16)((lo.y - (float)h[1]) * 2048.f);
        l[2] = (_Float16)((lo.z - (float)h[2]) * 2048.f);
        l[3] = (_Float16)((lo.w - (float)h[3]) * 2048.f);
        l[4] = (_Float16)((hi.x - (float)h[4]) * 2048.f);
        l[5] = (_Float16)((hi.y - (float)h[5]) * 2048.f);
        l[6] = (_Float16)((hi.z - (float)h[6]) * 2048.f);
        l[7] = (_Float16)((hi.w - (float)h[7]) * 2048.f);
        ah[s] = h; al[s] = l;
    }

    // ---- expval accumulators: 6 observables x 4 rows-per-lane ----
    float aX2[4] = {0, 0, 0, 0}, aY2[4] = {0, 0, 0, 0}, aZ2[4] = {0, 0, 0, 0};
    float aX6[4] = {0, 0, 0, 0}, aY6[4] = {0, 0, 0, 0}, aZ6[4] = {0, 0, 0, 0};

    const int l3 = lane & 7;
    const unsigned mY2 = (unsigned)(((l3 >> 2) ^ l3) & 1) << 31;
    const unsigned mY6 = (unsigned)(((l3 >> 1) ^ l3) & 1) << 31;
    const unsigned mZ2 = (unsigned)((l3 >> 2) & 1) << 31;
    const unsigned mZ6 = (unsigned)((l3 >> 1) & 1) << 31;

#pragma unroll 1
    for (int cc = 0; cc < 8; ++cc) {
        f32x4 accM[4], accC[4];
        const f32x4 zz = {0.f, 0.f, 0.f, 0.f};
#pragma unroll
        for (int i = 0; i < 4; ++i) { accM[i] = zz; accC[i] = zz; }

#pragma unroll
        for (int s = 0; s < 8; ++s) {
            const f16x8 a_h = ah[s];
            const f16x8 a_l = al[s];
#pragma unroll
            for (int nt = 0; nt < 4; ++nt) {
                const size_t boff = ((size_t)((cc * 4 + nt) * 8 + s) * 64 + lane) * 8;
                const f16x8 bh = *reinterpret_cast<const f16x8*>(&g_Bph[boff]);
                const f16x8 bl = *reinterpret_cast<const f16x8*>(&g_Bpl[boff]);
                accM[nt] = __builtin_amdgcn_mfma_f32_16x16x32_f16(a_h, bh, accM[nt], 0, 0, 0);
                accC[nt] = __builtin_amdgcn_mfma_f32_16x16x32_f16(a_l, bh, accC[nt], 0, 0, 0);
                accC[nt] = __builtin_amdgcn_mfma_f32_16x16x32_f16(a_h, bl, accC[nt], 0, 0, 0);
            }
        }
        // ---- per-chunk expval epilogue (validated) ----
#pragma unroll
        for (int nt = 0; nt < 4; ++nt) {
#pragma unroll
            for (int r = 0; r < 4; ++r) {
                const float val = fmaf(accC[nt][r], 4.8828125e-4f, accM[nt][r]);
                const float x4 = __shfl_xor(val, 4, 64);
                const float x2v = __shfl_xor(val, 2, 64);
                const float x5 = __shfl_xor(val, 5, 64);
                const float x3v = __shfl_xor(val, 3, 64);
                aX2[r] = fmaf(val, x4, aX2[r]);
                aX6[r] = fmaf(val, x2v, aX6[r]);
                aY2[r] = fmaf(xorf(val, mY2), x5, aY2[r]);
                aY6[r] = fmaf(xorf(val, mY6), x3v, aY6[r]);
                aZ2[r] = fmaf(xorf(val, mZ2), val, aZ2[r]);
                aZ6[r] = fmaf(xorf(val, mZ6), val, aZ6[r]);
            }
        }
    }

    // ---- final: reduce over the 16-lane col group, write 6 floats per row ----
#pragma unroll
    for (int r = 0; r < 4; ++r) {
#pragma unroll
        for (int o = 1; o <= 8; o <<= 1) {
            aX2[r] += __shfl_xor(aX2[r], o, 64);
            aY2[r] += __shfl_xor(aY2[r], o, 64);
            aZ2[r] += __shfl_xor(aZ2[r], o, 64);
            aX6[r] += __shfl_xor(aX6[r], o, 64);
            aY6[r] += __shfl_xor(aY6[r], o, 64);
            aZ6[r] += __shfl_xor(aZ6[r], o, 64);
        }
    }
    if (c16 == 0) {
        const size_t rowg = rowblk * 16 + oct * 4;
#pragma unroll
        for (int r = 0; r < 4; ++r) {
            float* o = out + (rowg + r) * 6;
            o[0] = aX2[r]; o[1] = aY2[r]; o[2] = aZ2[r];
            o[3] = aX6[r]; o[4] = aY6[r]; o[5] = aZ6[r];
        }
    }
}

extern "C" void kernel_launch(void* const* d_in, const int* in_sizes, int n_in,
                              void* d_out, int out_size, void* d_ws, size_t ws_size,
                              hipStream_t stream) {
    const float* x = (const float*)d_in[0];
    const float* w = (const float*)d_in[1];
    float* out = (float*)d_out;
    const int B = in_sizes[0] / DIM;  // 32768

    hipLaunchKernelGGL(qsvdd_setup, dim3(1), dim3(64), 0, stream, w);
    hipLaunchKernelGGL(build_u, dim3(16), dim3(256), 0, stream);
    hipLaunchKernelGGL(qsvdd_main, dim3(B / 64), dim3(256), 0, stream, x, out);
}

// Round 15
// 115.114 us; speedup vs baseline: 1.3873x; 1.3873x over previous
//
#include <hip/hip_runtime.h>

#define DIM 256  // 2^8 amplitudes

typedef _Float16 f16x8 __attribute__((ext_vector_type(8)));
typedef float f32x4 __attribute__((ext_vector_type(4)));

// 5 layer matrices, 4x4 complex each, row-major M[r*4+c]
__device__ float2 g_M[5 * 16];
// B = U^T (fp16 hi/lo split), packed in MFMA-fragment order:
// tile t = col-tile (0..31), s = k-step (0..7): element (lane, h):
// lane = oct*16+c16 holds col c16, k = s*32 + oct*8 + h. 1 KB per tile-step.
__device__ __align__(16) _Float16 g_Bph[32 * 8 * 64 * 8];
__device__ __align__(16) _Float16 g_Bpl[32 * 8 * 64 * 8];

__device__ inline float2 cmulc(float2 a, float2 b) {
    return make_float2(a.x * b.x - a.y * b.y, a.x * b.y + a.y * b.x);
}
__device__ inline float2 caddc(float2 a, float2 b) {
    return make_float2(a.x + b.x, a.y + b.y);
}

// ---------------- setup: build the 5 SU(4) gate matrices ----------------

__device__ void mat_u3(float t, float p, float l, float2* U) {
    float s, c;
    sincosf(0.5f * t, &s, &c);
    float sp, cp, sl, cl, spl, cpl;
    sincosf(p, &sp, &cp);
    sincosf(l, &sl, &cl);
    sincosf(p + l, &spl, &cpl);
    U[0] = make_float2(c, 0.f);
    U[1] = make_float2(-cl * s, -sl * s);
    U[2] = make_float2(cp * s, sp * s);
    U[3] = make_float2(cpl * c, spl * c);
}
__device__ void mat_ry(float t, float2* U) {
    float s, c;
    sincosf(0.5f * t, &s, &c);
    U[0] = make_float2(c, 0.f); U[1] = make_float2(-s, 0.f);
    U[2] = make_float2(s, 0.f); U[3] = make_float2(c, 0.f);
}
__device__ void mat_rz(float t, float2* U) {
    float s, c;
    sincosf(0.5f * t, &s, &c);
    U[0] = make_float2(c, -s); U[1] = make_float2(0.f, 0.f);
    U[2] = make_float2(0.f, 0.f); U[3] = make_float2(c, s);
}
__device__ void mat_I2(float2* U) {
    U[0] = make_float2(1.f, 0.f); U[1] = make_float2(0.f, 0.f);
    U[2] = make_float2(0.f, 0.f); U[3] = make_float2(1.f, 0.f);
}
__device__ void kron4(const float2* A, const float2* B, float2* K) {
    for (int i0 = 0; i0 < 2; ++i0)
        for (int i1 = 0; i1 < 2; ++i1)
            for (int j0 = 0; j0 < 2; ++j0)
                for (int j1 = 0; j1 < 2; ++j1)
                    K[(2 * i0 + i1) * 4 + (2 * j0 + j1)] = cmulc(A[i0 * 2 + j0], B[i1 * 2 + j1]);
}
__device__ void mm4(const float2* A, const float2* B, float2* C) {
    for (int r = 0; r < 4; ++r)
        for (int c = 0; c < 4; ++c) {
            float2 acc = make_float2(0.f, 0.f);
            for (int k = 0; k < 4; ++k) acc = caddc(acc, cmulc(A[r * 4 + k], B[k * 4 + c]));
            C[r * 4 + c] = acc;
        }
}
__device__ void swap_rows(float2* M, int r1, int r2) {
    for (int c = 0; c < 4; ++c) {
        float2 t = M[r1 * 4 + c]; M[r1 * 4 + c] = M[r2 * 4 + c]; M[r2 * 4 + c] = t;
    }
}

__global__ void qsvdd_setup(const float* __restrict__ w) {
    int l = threadIdx.x;
    if (l >= 5) return;
    const float* p = w + l * 15;
    float2 A[4], Bm[4], K[16], M[16], T[16];
    mat_u3(p[0], p[1], p[2], A);
    mat_u3(p[3], p[4], p[5], Bm);
    kron4(A, Bm, M);
    swap_rows(M, 2, 3);                       // CNOT01 @ M
    mat_ry(p[6], A); mat_rz(p[7], Bm);
    kron4(A, Bm, K); mm4(K, M, T);
    swap_rows(T, 1, 3);                       // CNOT10 @ M
    mat_ry(p[8], A); mat_I2(Bm);
    kron4(A, Bm, K); mm4(K, T, M);
    swap_rows(M, 2, 3);                       // CNOT01 @ M
    mat_u3(p[9], p[10], p[11], A);
    mat_u3(p[12], p[13], p[14], Bm);
    kron4(A, Bm, K); mm4(K, M, T);
    for (int i = 0; i < 16; ++i) g_M[l * 16 + i] = T[i];
}

// ---------------- circuit machinery (R8-validated, named registers) ----------------

__device__ __forceinline__ void cmadf(float2& a, float mx, float my, float2 v) {
    a.x = fmaf(mx, v.x, a.x);
    a.x = fmaf(-my, v.y, a.x);
    a.y = fmaf(mx, v.y, a.y);
    a.y = fmaf(my, v.x, a.y);
}
__device__ __forceinline__ float2 cmulf(float mx, float my, float2 v) {
    float2 r;
    r.x = mx * v.x; r.x = fmaf(-my, v.y, r.x);
    r.y = mx * v.y; r.y = fmaf(my, v.x, r.y);
    return r;
}
__device__ __forceinline__ float bperm(int ba, float s) {
    return __int_as_float(__builtin_amdgcn_ds_bpermute(ba, __float_as_int(s)));
}

#define GQ(A0, A1, A2, A3)                                                        \
    {                                                                             \
        float2 t0 = cmulf(m0.x, m0.y, A0);                                        \
        cmadf(t0, m1.x, m1.y, A1); cmadf(t0, m2.x, m2.y, A2); cmadf(t0, m3.x, m3.y, A3);   \
        float2 t1 = cmulf(m4.x, m4.y, A0);                                        \
        cmadf(t1, m5.x, m5.y, A1); cmadf(t1, m6.x, m6.y, A2); cmadf(t1, m7.x, m7.y, A3);   \
        float2 t2 = cmulf(m8.x, m8.y, A0);                                        \
        cmadf(t2, m9.x, m9.y, A1); cmadf(t2, m10.x, m10.y, A2); cmadf(t2, m11.x, m11.y, A3); \
        float2 t3 = cmulf(m12.x, m12.y, A0);                                      \
        cmadf(t3, m13.x, m13.y, A1); cmadf(t3, m14.x, m14.y, A2); cmadf(t3, m15.x, m15.y, A3); \
        A0 = t0; A1 = t1; A2 = t2; A3 = t3;                                       \
    }

#define G_32 { GQ(v0,v4,v8,v12)  GQ(v1,v5,v9,v13)  GQ(v2,v6,v10,v14) GQ(v3,v7,v11,v15) }
#define G_10 { GQ(v0,v1,v2,v3)   GQ(v4,v5,v6,v7)   GQ(v8,v9,v10,v11) GQ(v12,v13,v14,v15) }
#define G_21 { GQ(v0,v2,v4,v6)   GQ(v1,v3,v5,v7)   GQ(v8,v10,v12,v14) GQ(v9,v11,v13,v15) }
#define G_03 { GQ(v0,v8,v1,v9)   GQ(v2,v10,v3,v11) GQ(v4,v12,v5,v13) GQ(v6,v14,v7,v15) }
#define G_20 { GQ(v0,v1,v4,v5)   GQ(v2,v3,v6,v7)   GQ(v8,v9,v12,v13) GQ(v10,v11,v14,v15) }
#define G_13 { GQ(v0,v8,v2,v10)  GQ(v1,v9,v3,v11)  GQ(v4,v12,v6,v14) GQ(v5,v13,v7,v15) }
#define G_02 { GQ(v0,v4,v1,v5)   GQ(v2,v6,v3,v7)   GQ(v8,v12,v9,v13) GQ(v10,v14,v11,v15) }
#define G_30 { GQ(v0,v1,v8,v9)   GQ(v2,v3,v10,v11) GQ(v4,v5,v12,v13) GQ(v6,v7,v14,v15) }
#define G_23 { GQ(v0,v8,v4,v12)  GQ(v1,v9,v5,v13)  GQ(v2,v10,v6,v14) GQ(v3,v11,v7,v15) }
#define G_31 { GQ(v0,v2,v8,v10)  GQ(v1,v3,v9,v11)  GQ(v4,v6,v12,v14) GQ(v5,v7,v13,v15) }
#define G_12 { GQ(v0,v4,v2,v6)   GQ(v1,v5,v3,v7)   GQ(v8,v12,v10,v14) GQ(v9,v13,v11,v15) }

#define BSW(VA, VB, PB, BA)                                                       \
    {                                                                             \
        float sx = (PB) ? VA.x : VB.x, sy = (PB) ? VA.y : VB.y;                   \
        float rx = bperm(BA, sx), ry = bperm(BA, sy);                             \
        VA.x = (PB) ? rx : VA.x; VA.y = (PB) ? ry : VA.y;                         \
        VB.x = (PB) ? VB.x : rx; VB.y = (PB) ? VB.y : ry;                         \
    }

#define SW0(PB, BA) { BSW(v0,v1,PB,BA) BSW(v2,v3,PB,BA) BSW(v4,v5,PB,BA) BSW(v6,v7,PB,BA) \
                      BSW(v8,v9,PB,BA) BSW(v10,v11,PB,BA) BSW(v12,v13,PB,BA) BSW(v14,v15,PB,BA) }
#define SW1(PB, BA) { BSW(v0,v2,PB,BA) BSW(v1,v3,PB,BA) BSW(v4,v6,PB,BA) BSW(v5,v7,PB,BA) \
                      BSW(v8,v10,PB,BA) BSW(v9,v11,PB,BA) BSW(v12,v14,PB,BA) BSW(v13,v15,PB,BA) }
#define SW2(PB, BA) { BSW(v0,v4,PB,BA) BSW(v1,v5,PB,BA) BSW(v2,v6,PB,BA) BSW(v3,v7,PB,BA) \
                      BSW(v8,v12,PB,BA) BSW(v9,v13,PB,BA) BSW(v10,v14,PB,BA) BSW(v11,v15,PB,BA) }
#define SW3(PB, BA) { BSW(v0,v8,PB,BA) BSW(v1,v9,PB,BA) BSW(v2,v10,PB,BA) BSW(v3,v11,PB,BA) \
                      BSW(v4,v12,PB,BA) BSW(v5,v13,PB,BA) BSW(v6,v14,PB,BA) BSW(v7,v15,PB,BA) }

#define LOADM(L)                                                                  \
    {                                                                             \
        m0  = g_M[(L)*16+0];  m1  = g_M[(L)*16+1];  m2  = g_M[(L)*16+2];  m3  = g_M[(L)*16+3];  \
        m4  = g_M[(L)*16+4];  m5  = g_M[(L)*16+5];  m6  = g_M[(L)*16+6];  m7  = g_M[(L)*16+7];  \
        m8  = g_M[(L)*16+8];  m9  = g_M[(L)*16+9];  m10 = g_M[(L)*16+10]; m11 = g_M[(L)*16+11]; \
        m12 = g_M[(L)*16+12]; m13 = g_M[(L)*16+13]; m14 = g_M[(L)*16+14]; m15 = g_M[(L)*16+15]; \
    }

#define RUN_CIRCUIT                                                               \
    LOADM(0);                                                                     \
    G_32; G_10;                                                                   \
    SW3(p3, ba3); SW2(p2, ba2); SW1(p1, ba1); SW0(p0, ba0);                       \
    G_32; G_10;                                                                   \
    G_21;                                                                         \
    SW3(p3, ba3);                                                                 \
    G_03;                                                                         \
    SW1(p3, ba3); SW2(p0, ba0);                                                   \
    G_21;                                                                         \
    SW0(p2, ba2); SW3(p1, ba1);                                                   \
    G_03;                                                                         \
    LOADM(1);                                                                     \
    G_32;                                                                         \
    SW2(p1, ba1);                                                                 \
    G_20;                                                                         \
    SW3(p0, ba0);                                                                 \
    G_13;                                                                         \
    SW0(p3, ba3); SW2(p2, ba2);                                                   \
    G_02;                                                                         \
    G_30;                                                                         \
    SW3(p2, ba2);                                                                 \
    G_23;                                                                         \
    SW2(p1, ba1);                                                                 \
    G_21;                                                                         \
    SW0(p3, ba3); SW3(p0, ba0);                                                   \
    G_03;                                                                         \
    LOADM(2);                                                                     \
    G_31;                                                                         \
    SW2(p3, ba3); SW0(p0, ba0);                                                   \
    G_20;                                                                         \
    G_03; G_12;                                                                   \
    LOADM(3);                                                                     \
    G_31; G_20;                                                                   \
    G_03; G_12;                                                                   \
    LOADM(4);                                                                     \
    G_32;
// final layout: reg-index bits r0..r3 <-> amp bits {7,3,1,5};
// lane bits q0..q3 <-> amp bits {6,0,2,4}   (validated by R6/R8 passes)

// ---------------- build_u: U columns -> packed MFMA-fragment B (fp16 hi/lo) ----------------

__device__ __forceinline__ int pidx(int n, int c) {
    // n = permuted col (0..511), c = k (0..255) -> packed fragment index
    const int t = n >> 4, c16 = n & 15;
    const int s = c >> 5, oct = (c >> 3) & 3, h = c & 7;
    return (((t * 8 + s) * 64) + oct * 16 + c16) * 8 + h;
}

__device__ __forceinline__ void wru(float2 vv, int rb, int qb, int c) {
    const int a = ((rb & 1) << 7) | (((rb >> 1) & 1) << 3) | (((rb >> 2) & 1) << 1) |
                  (((rb >> 3) & 1) << 5) | qb;
    const int b7 = (a >> 7) & 1, b6 = (a >> 6) & 1, b5 = (a >> 5) & 1, b4 = (a >> 4) & 1;
    const int b3 = (a >> 3) & 1, b2 = (a >> 2) & 1, b1 = (a >> 1) & 1, b0 = a & 1;
    const int g = (b7 << 5) | (b6 << 4) | (b4 << 3) | (b3 << 2) | (b2 << 1) | b0;
    const int n = g * 8 + (((b5 << 1) | b1) << 1);
    const int i0 = pidx(n, c), i1 = pidx(n + 1, c);
    const _Float16 hr = (_Float16)vv.x, hi = (_Float16)vv.y;
    g_Bph[i0] = hr;
    g_Bph[i1] = hi;
    g_Bpl[i0] = (_Float16)((vv.x - (float)hr) * 2048.f);
    g_Bpl[i1] = (_Float16)((vv.y - (float)hi) * 2048.f);
}

__global__ __launch_bounds__(256) void build_u() {
    const int lane = threadIdx.x & 63;
    const int q = lane & 15;
    const int c = ((int)blockIdx.x * 4 + (threadIdx.x >> 6)) * 4 + (lane >> 4);

    const int ba0 = (lane ^ 1) << 2, ba1 = (lane ^ 2) << 2;
    const int ba2 = (lane ^ 4) << 2, ba3 = (lane ^ 8) << 2;
    const bool p0 = lane & 1, p1 = lane & 2, p2 = lane & 4, p3 = lane & 8;

    // basis state e_c  (amp index = r*16 + q)
    float2 v0, v1, v2, v3, v4, v5, v6, v7, v8, v9, v10, v11, v12, v13, v14, v15;
    v0  = make_float2((0*16+q)  == c ? 1.f : 0.f, 0.f);
    v1  = make_float2((1*16+q)  == c ? 1.f : 0.f, 0.f);
    v2  = make_float2((2*16+q)  == c ? 1.f : 0.f, 0.f);
    v3  = make_float2((3*16+q)  == c ? 1.f : 0.f, 0.f);
    v4  = make_float2((4*16+q)  == c ? 1.f : 0.f, 0.f);
    v5  = make_float2((5*16+q)  == c ? 1.f : 0.f, 0.f);
    v6  = make_float2((6*16+q)  == c ? 1.f : 0.f, 0.f);
    v7  = make_float2((7*16+q)  == c ? 1.f : 0.f, 0.f);
    v8  = make_float2((8*16+q)  == c ? 1.f : 0.f, 0.f);
    v9  = make_float2((9*16+q)  == c ? 1.f : 0.f, 0.f);
    v10 = make_float2((10*16+q) == c ? 1.f : 0.f, 0.f);
    v11 = make_float2((11*16+q) == c ? 1.f : 0.f, 0.f);
    v12 = make_float2((12*16+q) == c ? 1.f : 0.f, 0.f);
    v13 = make_float2((13*16+q) == c ? 1.f : 0.f, 0.f);
    v14 = make_float2((14*16+q) == c ? 1.f : 0.f, 0.f);
    v15 = make_float2((15*16+q) == c ? 1.f : 0.f, 0.f);

    float2 m0, m1, m2, m3, m4, m5, m6, m7, m8, m9, m10, m11, m12, m13, m14, m15;
    RUN_CIRCUIT;

    const int qb = ((q & 1) << 6) | (((q >> 1) & 1) << 0) | (((q >> 2) & 1) << 2) |
                   (((q >> 3) & 1) << 4);
    wru(v0, 0, qb, c);   wru(v1, 1, qb, c);   wru(v2, 2, qb, c);   wru(v3, 3, qb, c);
    wru(v4, 4, qb, c);   wru(v5, 5, qb, c);   wru(v6, 6, qb, c);   wru(v7, 7, qb, c);
    wru(v8, 8, qb, c);   wru(v9, 9, qb, c);   wru(v10, 10, qb, c); wru(v11, 11, qb, c);
    wru(v12, 12, qb, c); wru(v13, 13, qb, c); wru(v14, 14, qb, c); wru(v15, 15, qb, c);
}

// ---------------- main: col-split 3-term fp16-split GEMM + fused expvals ----------------
//
// Block = 16 rows; 4 waves each own a 128-col quarter (8 tiles). 8192 waves
// (8/SIMD available). NUMERICS = R9/R11-validated fp16 hi/lo split (R14's
// pure-fp16 measured 4.6e-2, 8x over threshold — corrections are required).
// Normalization post-GEMM (expvals bilinear -> scale by 1/||x||^2, exact
// fp32 divide). Cross-wave partials via 1.5 KB LDS + one barrier.

__device__ __forceinline__ float xorf(float v, unsigned m) {
    return __int_as_float(__float_as_int(v) ^ (int)m);
}

__global__ __launch_bounds__(256, 3) void qsvdd_main(const float* __restrict__ x,
                                                     float* __restrict__ out) {
    __shared__ float sPart[4][16][6];

    const int lane = threadIdx.x & 63;
    const int w = threadIdx.x >> 6;
    const int c16 = lane & 15;
    const int oct = lane >> 4;

    // ---- load A fragments (raw x), ssq, fp16 hi/lo split in registers ----
    const float* ax = x + (size_t)blockIdx.x * 16 * 256 + (size_t)c16 * 256 + oct * 8;
    float ssq = 0.f;
    f16x8 ah[8], al[8];
#pragma unroll
    for (int s = 0; s < 8; ++s) {
        const f32x4 lo = *reinterpret_cast<const f32x4*>(ax + s * 32);
        const f32x4 hi = *reinterpret_cast<const f32x4*>(ax + s * 32 + 4);
        ssq = fmaf(lo.x, lo.x, ssq); ssq = fmaf(lo.y, lo.y, ssq);
        ssq = fmaf(lo.z, lo.z, ssq); ssq = fmaf(lo.w, lo.w, ssq);
        ssq = fmaf(hi.x, hi.x, ssq); ssq = fmaf(hi.y, hi.y, ssq);
        ssq = fmaf(hi.z, hi.z, ssq); ssq = fmaf(hi.w, hi.w, ssq);
        f16x8 h, l;
        h[0] = (_Float16)lo.x; h[1] = (_Float16)lo.y; h[2] = (_Float16)lo.z; h[3] = (_Float16)lo.w;
        h[4] = (_Float16)hi.x; h[5] = (_Float16)hi.y; h[6] = (_Float16)hi.z; h[7] = (_Float16)hi.w;
        l[0] = (_Float16)((lo.x - (float)h[0]) * 2048.f);
        l[1] = (_Float16)((lo.y - (float)h[1]) * 2048.f);
        l[2] = (_Float16)((lo.z - (float)h[2]) * 2048.f);
        l[3] = (_Float16)((lo.w - (float)h[3]) * 2048.f);
        l[4] = (_Float16)((hi.x - (float)h[4]) * 2048.f);
        l[5] = (_Float16)((hi.y - (float)h[5]) * 2048.f);
        l[6] = (_Float16)((hi.z - (float)h[6]) * 2048.f);
        l[7] = (_Float16)((hi.w - (float)h[7]) * 2048.f);
        ah[s] = h; al[s] = l;
    }
    // full-row ssq: every lane ends with the sum for its row c16
    ssq += __shfl_xor(ssq, 16, 64);
    ssq += __shfl_xor(ssq, 32, 64);

    // per-row inverse norms, UNIFORM control flow (R13 lesson)
    float isr[4];
#pragma unroll
    for (int r = 0; r < 4; ++r) isr[r] = 1.0f / __shfl(ssq, oct * 4 + r, 64);

    // ---- GEMM: this wave's 8 col-tiles (cols w*128 ..), 3-term split ----
    f32x4 accM[8], accC[8];
    const f32x4 zz = {0.f, 0.f, 0.f, 0.f};
#pragma unroll
    for (int i = 0; i < 8; ++i) { accM[i] = zz; accC[i] = zz; }

#pragma unroll
    for (int s = 0; s < 8; ++s) {
        const f16x8 a_h = ah[s];
        const f16x8 a_l = al[s];
#pragma unroll
        for (int nt = 0; nt < 8; ++nt) {
            const size_t boff = ((size_t)(((w * 8 + nt) * 8) + s) * 64 + lane) * 8;
            const f16x8 bh = *reinterpret_cast<const f16x8*>(&g_Bph[boff]);
            const f16x8 bl = *reinterpret_cast<const f16x8*>(&g_Bpl[boff]);
            accM[nt] = __builtin_amdgcn_mfma_f32_16x16x32_f16(a_h, bh, accM[nt], 0, 0, 0);
            accC[nt] = __builtin_amdgcn_mfma_f32_16x16x32_f16(a_l, bh, accC[nt], 0, 0, 0);
            accC[nt] = __builtin_amdgcn_mfma_f32_16x16x32_f16(a_h, bl, accC[nt], 0, 0, 0);
        }
    }

    // ---- expval epilogue (per-tile pair shuffles, validated R9/R11) ----
    float aX2[4] = {0, 0, 0, 0}, aY2[4] = {0, 0, 0, 0}, aZ2[4] = {0, 0, 0, 0};
    float aX6[4] = {0, 0, 0, 0}, aY6[4] = {0, 0, 0, 0}, aZ6[4] = {0, 0, 0, 0};

    const int l3 = lane & 7;
    const unsigned mY2 = (unsigned)(((l3 >> 2) ^ l3) & 1) << 31;
    const unsigned mY6 = (unsigned)(((l3 >> 1) ^ l3) & 1) << 31;
    const unsigned mZ2 = (unsigned)((l3 >> 2) & 1) << 31;
    const unsigned mZ6 = (unsigned)((l3 >> 1) & 1) << 31;

#pragma unroll
    for (int nt = 0; nt < 8; ++nt) {
#pragma unroll
        for (int r = 0; r < 4; ++r) {
            const float val = fmaf(accC[nt][r], 4.8828125e-4f, accM[nt][r]);
            const float x4 = __shfl_xor(val, 4, 64);
            const float x2v = __shfl_xor(val, 2, 64);
            const float x5 = __shfl_xor(val, 5, 64);
            const float x3v = __shfl_xor(val, 3, 64);
            aX2[r] = fmaf(val, x4, aX2[r]);
            aX6[r] = fmaf(val, x2v, aX6[r]);
            aY2[r] = fmaf(xorf(val, mY2), x5, aY2[r]);
            aY6[r] = fmaf(xorf(val, mY6), x3v, aY6[r]);
            aZ2[r] = fmaf(xorf(val, mZ2), val, aZ2[r]);
            aZ6[r] = fmaf(xorf(val, mZ6), val, aZ6[r]);
        }
    }

    // reduce over the 16-lane col group
#pragma unroll
    for (int r = 0; r < 4; ++r) {
#pragma unroll
        for (int o = 1; o <= 8; o <<= 1) {
            aX2[r] += __shfl_xor(aX2[r], o, 64);
            aY2[r] += __shfl_xor(aY2[r], o, 64);
            aZ2[r] += __shfl_xor(aZ2[r], o, 64);
            aX6[r] += __shfl_xor(aX6[r], o, 64);
            aY6[r] += __shfl_xor(aY6[r], o, 64);
            aZ6[r] += __shfl_xor(aZ6[r], o, 64);
        }
    }

    // scale by 1/||x||^2 and stash per-wave partials (no shuffles in here)
    if (c16 == 0) {
#pragma unroll
        for (int r = 0; r < 4; ++r) {
            const int row = oct * 4 + r;
            sPart[w][row][0] = aX2[r] * isr[r];
            sPart[w][row][1] = aY2[r] * isr[r];
            sPart[w][row][2] = aZ2[r] * isr[r];
            sPart[w][row][3] = aX6[r] * isr[r];
            sPart[w][row][4] = aY6[r] * isr[r];
            sPart[w][row][5] = aZ6[r] * isr[r];
        }
    }
    __syncthreads();

    // sum the 4 col-quarter partials, write 16 rows x 6
    if (threadIdx.x < 96) {
        const int row = threadIdx.x / 6, ob = threadIdx.x % 6;
        const float sum = sPart[0][row][ob] + sPart[1][row][ob] +
                          sPart[2][row][ob] + sPart[3][row][ob];
        out[((size_t)blockIdx.x * 16 + row) * 6 + ob] = sum;
    }
}

extern "C" void kernel_launch(void* const* d_in, const int* in_sizes, int n_in,
                              void* d_out, int out_size, void* d_ws, size_t ws_size,
                              hipStream_t stream) {
    const float* x = (const float*)d_in[0];
    const float* w = (const float*)d_in[1];
    float* out = (float*)d_out;
    const int B = in_sizes[0] / DIM;  // 32768

    hipLaunchKernelGGL(qsvdd_setup, dim3(1), dim3(64), 0, stream, w);
    hipLaunchKernelGGL(build_u, dim3(16), dim3(256), 0, stream);
    hipLaunchKernelGGL(qsvdd_main, dim3(B / 16), dim3(256), 0, stream, x, out);
}